// Round 1
// baseline (355.538 us; speedup 1.0000x reference)
//
#include <hip/hip_runtime.h>
#include <math.h>

#define Nn 10000
#define Ee 160000
#define Cc 64
#define NBb 8
#define Gg 100

// Static device scratch (~57 MB) — avoids dependence on ws_size.
__device__ float g_sh[9 * Ee];          // SoA: g_sh[m*Ee + e]
__device__ float g_R[Ee * Cc];          // AoS: g_R[e*64 + c]
__device__ float g_h[2][Nn * Cc];       // ping-pong h
__device__ float g_h1[Nn * Cc];         // h @ W_up[l]
__device__ float g_hsc[Nn * Cc];        // h @ W_sc[l]
__device__ int   g_deg[Nn];
__device__ int   g_offs[Nn + 1];
__device__ int   g_cursor[Nn];
__device__ int   g_csr[Ee];

__global__ __launch_bounds__(256) void k_zero(float* out, int out_size) {
    int i = blockIdx.x * 256 + threadIdx.x;
    if (i < out_size) out[i] = 0.0f;
    if (i < Nn) { g_deg[i] = 0; g_cursor[i] = 0; }
}

// Per-edge: geometry -> spherical harmonics + radial MLP -> R (E x 64)
__global__ __launch_bounds__(256) void k_edge(const float* __restrict__ pos,
                                              const float* __restrict__ Wr1,
                                              const float* __restrict__ br1,
                                              const float* __restrict__ Wr2,
                                              const int* __restrict__ eidx) {
    __shared__ float sWr1[NBb * 64];
    __shared__ float sbr1[64];
    __shared__ float sWr2[64 * 64];
    int t = threadIdx.x;
    for (int i = t; i < NBb * 64; i += 256) sWr1[i] = Wr1[i];
    if (t < 64) sbr1[t] = br1[t];
    for (int i = t; i < 64 * 64; i += 256) sWr2[i] = Wr2[i];
    __syncthreads();

    int e = blockIdx.x * 256 + t;
    if (e >= Ee) return;
    int snd = eidx[e];
    int rcv = eidx[Ee + e];
    float vx = pos[3 * rcv + 0] - pos[3 * snd + 0];
    float vy = pos[3 * rcv + 1] - pos[3 * snd + 1];
    float vz = pos[3 * rcv + 2] - pos[3 * snd + 2];
    float r = sqrtf(vx * vx + vy * vy + vz * vz);
    float rs = fmaxf(r, 1e-9f);
    float inv = 1.0f / rs;
    float x = vx * inv, y = vy * inv, z = vz * inv;
    const float s3 = 1.7320508f;
    g_sh[0 * Ee + e] = 1.0f;
    g_sh[1 * Ee + e] = x;
    g_sh[2 * Ee + e] = y;
    g_sh[3 * Ee + e] = z;
    g_sh[4 * Ee + e] = s3 * x * y;
    g_sh[5 * Ee + e] = s3 * y * z;
    g_sh[6 * Ee + e] = 0.5f * (3.0f * z * z - 1.0f);
    g_sh[7 * Ee + e] = s3 * x * z;
    g_sh[8 * Ee + e] = 0.5f * s3 * (x * x - y * y);

    // radial embedding
    float xx = r * 0.2f;  // r / R_MAX
    float env = 0.0f;
    if (xx < 1.0f) {
        float x2 = xx * xx;
        float x6 = x2 * x2 * x2;
        float x7 = x6 * xx;
        float x8 = x7 * xx;
        env = 1.0f - 28.0f * x6 + 48.0f * x7 - 21.0f * x8;
    }
    const float pref = 0.63245553f;  // sqrt(2/R_MAX)
    const float PI_F = 3.14159265358979f;
    float fac = pref * inv * env;
    float ef[NBb];
#pragma unroll
    for (int k = 0; k < NBb; k++) {
        float ang = (float)(k + 1) * PI_F * r * 0.2f;
        ef[k] = fac * sinf(ang);
    }

    float acc[64];
#pragma unroll
    for (int c = 0; c < 64; c++) acc[c] = 0.0f;
    for (int j = 0; j < 64; j++) {
        float hj = sbr1[j];
#pragma unroll
        for (int k = 0; k < NBb; k++) hj += ef[k] * sWr1[k * 64 + j];
        // silu
        hj = hj / (1.0f + __expf(-hj));
#pragma unroll
        for (int c = 0; c < 64; c++) acc[c] += hj * sWr2[j * 64 + c];
    }
    float4* dst = (float4*)&g_R[e * 64];
#pragma unroll
    for (int c4 = 0; c4 < 16; c4++)
        dst[c4] = make_float4(acc[4 * c4], acc[4 * c4 + 1], acc[4 * c4 + 2], acc[4 * c4 + 3]);
}

__global__ __launch_bounds__(256) void k_deg(const int* __restrict__ eidx) {
    int e = blockIdx.x * 256 + threadIdx.x;
    if (e < Ee) atomicAdd(&g_deg[eidx[Ee + e]], 1);
}

__global__ __launch_bounds__(1024) void k_scan() {
    __shared__ int part[1024];
    int t = threadIdx.x;
    const int CH = (Nn + 1023) / 1024;  // 10
    int st = t * CH;
    int en = st + CH; if (en > Nn) en = Nn;
    int s = 0;
    for (int i = st; i < en; i++) s += g_deg[i];
    part[t] = s;
    __syncthreads();
    for (int d = 1; d < 1024; d <<= 1) {
        int v = (t >= d) ? part[t - d] : 0;
        __syncthreads();
        part[t] += v;
        __syncthreads();
    }
    int base = (t == 0) ? 0 : part[t - 1];
    for (int i = st; i < en; i++) { g_offs[i] = base; base += g_deg[i]; }
    if (t == 1023) g_offs[Nn] = part[1023];
}

__global__ __launch_bounds__(256) void k_fill(const int* __restrict__ eidx) {
    int e = blockIdx.x * 256 + threadIdx.x;
    if (e >= Ee) return;
    int r = eidx[Ee + e];
    int p = g_offs[r] + atomicAdd(&g_cursor[r], 1);
    g_csr[p] = e;
}

__global__ __launch_bounds__(256) void k_hinit(const float* __restrict__ W_embed,
                                               const int* __restrict__ atom_types) {
    int i = blockIdx.x * 256 + threadIdx.x;
    if (i >= Nn * Cc) return;
    int n = i >> 6, c = i & 63;
    g_h[0][i] = W_embed[atom_types[n] * Cc + c];
}

// h1 = h @ W_up[l], hsc = h @ W_sc[l]; wave per node, lane = out channel
__global__ __launch_bounds__(256) void k_lin(const float* __restrict__ Wup,
                                             const float* __restrict__ Wsc, int l) {
    __shared__ float sU[4096];
    __shared__ float sS[4096];
    int t = threadIdx.x;
    for (int i = t; i < 4096; i += 256) { sU[i] = Wup[i]; sS[i] = Wsc[i]; }
    __syncthreads();
    int node = blockIdx.x * 4 + (t >> 6);
    int lane = t & 63;
    const float* hin = g_h[l & 1];
    float hv = hin[node * 64 + lane];
    float a1 = 0.0f, a2 = 0.0f;
#pragma unroll
    for (int k = 0; k < 64; k++) {
        float hk = __shfl(hv, k, 64);
        a1 += hk * sU[k * 64 + lane];
        a2 += hk * sS[k * 64 + lane];
    }
    g_h1[node * 64 + lane] = a1;
    g_hsc[node * 64 + lane] = a2;
}

// Gather A per node via CSR, q, h_new = q@W_prod + hsc, node energy
__global__ __launch_bounds__(256) void k_node(const float* __restrict__ Wprod,
                                              const float* __restrict__ wro,
                                              const int* __restrict__ eidx,
                                              const int* __restrict__ batch,
                                              int l, float* __restrict__ out) {
    __shared__ float sP[4096];
    int t = threadIdx.x;
    for (int i = t; i < 4096; i += 256) sP[i] = Wprod[i];
    __syncthreads();
    int node = blockIdx.x * 4 + (t >> 6);
    int lane = t & 63;
    float A[9];
#pragma unroll
    for (int m = 0; m < 9; m++) A[m] = 0.0f;
    int beg = g_offs[node], en = g_offs[node + 1];
    for (int j = beg; j < en; j++) {
        int e = g_csr[j];
        int snd = eidx[e];
        float tv = g_R[e * 64 + lane] * g_h1[snd * 64 + lane];
#pragma unroll
        for (int m = 0; m < 9; m++) A[m] += g_sh[m * Ee + e] * tv;
    }
    const float invn = 1.0f / 16.0f;  // AVG_NEI
    float q = A[0] * invn;
#pragma unroll
    for (int m = 0; m < 9; m++) {
        float a = A[m] * invn;
        q += a * a;
    }
    float hn = g_hsc[node * 64 + lane];
#pragma unroll
    for (int k = 0; k < 64; k++) {
        float qk = __shfl(q, k, 64);
        hn += qk * sP[k * 64 + lane];
    }
    float* hout = g_h[(l + 1) & 1];
    hout[node * 64 + lane] = hn;
    float v = hn * wro[lane];
#pragma unroll
    for (int off = 32; off > 0; off >>= 1) v += __shfl_down(v, off, 64);
    if (lane == 0) atomicAdd(&out[batch[node]], v);
}

extern "C" void kernel_launch(void* const* d_in, const int* in_sizes, int n_in,
                              void* d_out, int out_size, void* d_ws, size_t ws_size,
                              hipStream_t stream) {
    const float* pos     = (const float*)d_in[0];
    const float* W_embed = (const float*)d_in[1];
    const float* W_r1    = (const float*)d_in[2];
    const float* b_r1    = (const float*)d_in[3];
    const float* W_r2    = (const float*)d_in[4];
    const float* W_up    = (const float*)d_in[5];
    const float* W_sc    = (const float*)d_in[6];
    const float* W_prod  = (const float*)d_in[7];
    const float* w_ro    = (const float*)d_in[8];
    const int* atom_types = (const int*)d_in[9];
    const int* eidx       = (const int*)d_in[10];
    const int* batch      = (const int*)d_in[11];
    float* out = (float*)d_out;

    k_zero<<<(Nn + 255) / 256, 256, 0, stream>>>(out, out_size);
    k_edge<<<Ee / 256, 256, 0, stream>>>(pos, W_r1, b_r1, W_r2, eidx);
    k_deg<<<Ee / 256, 256, 0, stream>>>(eidx);
    k_scan<<<1, 1024, 0, stream>>>();
    k_fill<<<Ee / 256, 256, 0, stream>>>(eidx);
    k_hinit<<<(Nn * Cc) / 256, 256, 0, stream>>>(W_embed, atom_types);
    for (int l = 0; l < 2; l++) {
        k_lin<<<Nn / 4, 256, 0, stream>>>(W_up + l * 4096, W_sc + l * 4096, l);
        k_node<<<Nn / 4, 256, 0, stream>>>(W_prod + l * 4096, w_ro + l * 64, eidx, batch, l, out);
    }
}

// Round 3
// 351.438 us; speedup vs baseline: 1.0117x; 1.0117x over previous
//
#include <hip/hip_runtime.h>
#include <math.h>

#define Nn 10000
#define Ee 160000
#define NBb 8

// Static device scratch — slot-ordered (CSR order) edge data for streaming reads.
__device__ __align__(16) float g_shc[Ee * 12];  // [slot][12] (9 used, pad to 48B)
__device__ __align__(16) float g_Rc[Ee * 64];   // [slot][64]
__device__ int   g_src[Ee];                     // [slot] sender node
__device__ float g_h[2][Nn * 64];
__device__ float g_h1[Nn * 64];
__device__ float g_hsc[Nn * 64];
__device__ int   g_deg[Nn];
__device__ int   g_offs[Nn + 1];
__device__ int   g_cursor[Nn];
__device__ int   g_csr[Ee];

__global__ __launch_bounds__(256) void k_zero(float* out, int out_size) {
    int i = blockIdx.x * 256 + threadIdx.x;
    if (i < out_size) out[i] = 0.0f;
    if (i < Nn) { g_deg[i] = 0; g_cursor[i] = 0; }
}

__global__ __launch_bounds__(256) void k_deg(const int* __restrict__ eidx) {
    int e = blockIdx.x * 256 + threadIdx.x;
    if (e < Ee) atomicAdd(&g_deg[eidx[Ee + e]], 1);
}

__global__ __launch_bounds__(1024) void k_scan() {
    __shared__ int part[1024];
    int t = threadIdx.x;
    const int CH = (Nn + 1023) / 1024;  // 10
    int st = t * CH;
    int en = st + CH; if (en > Nn) en = Nn;
    int s = 0;
    for (int i = st; i < en; i++) s += g_deg[i];
    part[t] = s;
    __syncthreads();
    for (int d = 1; d < 1024; d <<= 1) {
        int v = (t >= d) ? part[t - d] : 0;
        __syncthreads();
        part[t] += v;
        __syncthreads();
    }
    int base = (t == 0) ? 0 : part[t - 1];
    for (int i = st; i < en; i++) { g_offs[i] = base; base += g_deg[i]; }
    if (t == 1023) g_offs[Nn] = part[1023];
}

__global__ __launch_bounds__(256) void k_fill(const int* __restrict__ eidx) {
    int e = blockIdx.x * 256 + threadIdx.x;
    if (e >= Ee) return;
    int r = eidx[Ee + e];
    int p = g_offs[r] + atomicAdd(&g_cursor[r], 1);
    g_csr[p] = e;
}

// Per-edge geometry + radial MLP, written in CSR slot order.
// 2 edges per thread so each W2 LDS broadcast read feeds 2 FMA streams.
__global__ __launch_bounds__(256, 1) void k_edge(const float* __restrict__ pos,
                                                 const float* __restrict__ Wr1,
                                                 const float* __restrict__ br1,
                                                 const float* __restrict__ Wr2,
                                                 const int* __restrict__ eidx) {
    __shared__ float sWr1[NBb * 64];
    __shared__ float sbr1[64];
    __shared__ float4 sWr2[64 * 16];  // [j][c4]
    int t = threadIdx.x;
    for (int i = t; i < NBb * 64; i += 256) sWr1[i] = Wr1[i];
    if (t < 64) sbr1[t] = br1[t];
    for (int i = t; i < 64 * 16; i += 256) {
        const float* w = &Wr2[i * 4];
        sWr2[i] = make_float4(w[0], w[1], w[2], w[3]);
    }
    __syncthreads();

    int i = blockIdx.x * 256 + t;
    int s0 = 2 * i, s1 = 2 * i + 1;
    if (s0 >= Ee) return;
    int e0 = g_csr[s0], e1 = g_csr[s1];

    float ef0[NBb], ef1[NBb];
    const float s3 = 1.7320508f;
    const float pref = 0.63245553f;  // sqrt(2/R_MAX)
    const float PI_F = 3.14159265358979f;
#pragma unroll
    for (int q = 0; q < 2; q++) {
        int e = q ? e1 : e0;
        int s = q ? s1 : s0;
        int snd = eidx[e];
        int rcv = eidx[Ee + e];
        float vx = pos[3 * rcv + 0] - pos[3 * snd + 0];
        float vy = pos[3 * rcv + 1] - pos[3 * snd + 1];
        float vz = pos[3 * rcv + 2] - pos[3 * snd + 2];
        float r = sqrtf(vx * vx + vy * vy + vz * vz);
        float inv = 1.0f / fmaxf(r, 1e-9f);
        float x = vx * inv, y = vy * inv, z = vz * inv;
        float4* shp = (float4*)(g_shc + (size_t)s * 12);
        shp[0] = make_float4(1.0f, x, y, z);
        shp[1] = make_float4(s3 * x * y, s3 * y * z, 0.5f * (3.0f * z * z - 1.0f), s3 * x * z);
        shp[2] = make_float4(0.5f * s3 * (x * x - y * y), 0.0f, 0.0f, 0.0f);
        g_src[s] = snd;
        float xx = r * 0.2f;
        float env = 0.0f;
        if (xx < 1.0f) {
            float x2 = xx * xx;
            float x6 = x2 * x2 * x2;
            float x7 = x6 * xx;
            float x8 = x7 * xx;
            env = 1.0f - 28.0f * x6 + 48.0f * x7 - 21.0f * x8;
        }
        float fac = pref * inv * env;
        float* ef = q ? ef1 : ef0;
#pragma unroll
        for (int k = 0; k < NBb; k++)
            ef[k] = fac * sinf((float)(k + 1) * PI_F * r * 0.2f);
    }

    float4 acc0[16], acc1[16];
#pragma unroll
    for (int c = 0; c < 16; c++) {
        acc0[c] = make_float4(0.f, 0.f, 0.f, 0.f);
        acc1[c] = make_float4(0.f, 0.f, 0.f, 0.f);
    }
    for (int j = 0; j < 64; j++) {
        float a0 = sbr1[j], a1 = a0;
#pragma unroll
        for (int k = 0; k < NBb; k++) {
            float w = sWr1[k * 64 + j];
            a0 += ef0[k] * w;
            a1 += ef1[k] * w;
        }
        a0 = a0 / (1.0f + __expf(-a0));
        a1 = a1 / (1.0f + __expf(-a1));
#pragma unroll
        for (int c = 0; c < 16; c++) {
            float4 w = sWr2[j * 16 + c];
            acc0[c].x += a0 * w.x; acc0[c].y += a0 * w.y;
            acc0[c].z += a0 * w.z; acc0[c].w += a0 * w.w;
            acc1[c].x += a1 * w.x; acc1[c].y += a1 * w.y;
            acc1[c].z += a1 * w.z; acc1[c].w += a1 * w.w;
        }
    }
    float4* d0 = (float4*)(g_Rc + (size_t)s0 * 64);
    float4* d1 = (float4*)(g_Rc + (size_t)s1 * 64);
#pragma unroll
    for (int c = 0; c < 16; c++) { d0[c] = acc0[c]; d1[c] = acc1[c]; }
}

__global__ __launch_bounds__(256) void k_hinit(const float* __restrict__ W_embed,
                                               const int* __restrict__ atom_types) {
    int i = blockIdx.x * 256 + threadIdx.x;
    if (i >= Nn * 64) return;
    int n = i >> 6, c = i & 63;
    g_h[0][i] = W_embed[atom_types[n] * 64 + c];
}

__global__ __launch_bounds__(256) void k_lin(const float* __restrict__ Wup,
                                             const float* __restrict__ Wsc, int l) {
    __shared__ float sU[4096];
    __shared__ float sS[4096];
    int t = threadIdx.x;
    for (int i = t; i < 4096; i += 256) { sU[i] = Wup[i]; sS[i] = Wsc[i]; }
    __syncthreads();
    int node = blockIdx.x * 4 + (t >> 6);
    int lane = t & 63;
    const float* hin = g_h[l & 1];
    float hv = hin[node * 64 + lane];
    float a1 = 0.0f, a2 = 0.0f;
#pragma unroll
    for (int k = 0; k < 64; k++) {
        float hk = __shfl(hv, k, 64);
        a1 += hk * sU[k * 64 + lane];
        a2 += hk * sS[k * 64 + lane];
    }
    g_h1[node * 64 + lane] = a1;
    g_hsc[node * 64 + lane] = a2;
}

// Streaming gather: R/sh/src are in CSR order -> sequential; only h1 is a gather.
__global__ __launch_bounds__(256) void k_node(const float* __restrict__ Wprod,
                                              const float* __restrict__ wro,
                                              const int* __restrict__ batch,
                                              int l, float* __restrict__ out) {
    __shared__ float sP[4096];
    int t = threadIdx.x;
    for (int i = t; i < 4096; i += 256) sP[i] = Wprod[i];
    __syncthreads();
    int node = blockIdx.x * 4 + (t >> 6);
    int lane = t & 63;
    int beg = __builtin_amdgcn_readfirstlane(g_offs[node]);
    int en  = __builtin_amdgcn_readfirstlane(g_offs[node + 1]);
    float A[9];
#pragma unroll
    for (int m = 0; m < 9; m++) A[m] = 0.0f;

    int j = beg;
    for (; j + 2 <= en; j += 2) {
        int s0 = __builtin_amdgcn_readfirstlane(g_src[j]);
        int s1 = __builtin_amdgcn_readfirstlane(g_src[j + 1]);
        float r0 = g_Rc[(size_t)j * 64 + lane];
        float r1 = g_Rc[(size_t)(j + 1) * 64 + lane];
        float h0 = g_h1[s0 * 64 + lane];
        float h1v = g_h1[s1 * 64 + lane];
        const float4* p0 = (const float4*)(g_shc + (size_t)j * 12);
        const float4* p1 = (const float4*)(g_shc + (size_t)(j + 1) * 12);
        float4 u0 = p0[0], u1 = p0[1], u2 = p0[2];
        float4 v0 = p1[0], v1 = p1[1], v2 = p1[2];
        float tv0 = r0 * h0, tv1 = r1 * h1v;
        A[0] += u0.x * tv0 + v0.x * tv1;
        A[1] += u0.y * tv0 + v0.y * tv1;
        A[2] += u0.z * tv0 + v0.z * tv1;
        A[3] += u0.w * tv0 + v0.w * tv1;
        A[4] += u1.x * tv0 + v1.x * tv1;
        A[5] += u1.y * tv0 + v1.y * tv1;
        A[6] += u1.z * tv0 + v1.z * tv1;
        A[7] += u1.w * tv0 + v1.w * tv1;
        A[8] += u2.x * tv0 + v2.x * tv1;
    }
    for (; j < en; j++) {
        int s0 = __builtin_amdgcn_readfirstlane(g_src[j]);
        float tv = g_Rc[(size_t)j * 64 + lane] * g_h1[s0 * 64 + lane];
        const float4* p0 = (const float4*)(g_shc + (size_t)j * 12);
        float4 u0 = p0[0], u1 = p0[1], u2 = p0[2];
        A[0] += u0.x * tv; A[1] += u0.y * tv; A[2] += u0.z * tv;
        A[3] += u0.w * tv; A[4] += u1.x * tv; A[5] += u1.y * tv;
        A[6] += u1.z * tv; A[7] += u1.w * tv; A[8] += u2.x * tv;
    }

    const float invn = 1.0f / 16.0f;  // AVG_NEI
    float q = A[0] * invn;
#pragma unroll
    for (int m = 0; m < 9; m++) {
        float a = A[m] * invn;
        q += a * a;
    }
    float hn = g_hsc[node * 64 + lane];
#pragma unroll
    for (int k = 0; k < 64; k++) {
        float qk = __shfl(q, k, 64);
        hn += qk * sP[k * 64 + lane];
    }
    float* hout = g_h[(l + 1) & 1];
    hout[node * 64 + lane] = hn;
    float v = hn * wro[lane];
#pragma unroll
    for (int off = 32; off > 0; off >>= 1) v += __shfl_down(v, off, 64);
    if (lane == 0) atomicAdd(&out[batch[node]], v);
}

extern "C" void kernel_launch(void* const* d_in, const int* in_sizes, int n_in,
                              void* d_out, int out_size, void* d_ws, size_t ws_size,
                              hipStream_t stream) {
    const float* pos     = (const float*)d_in[0];
    const float* W_embed = (const float*)d_in[1];
    const float* W_r1    = (const float*)d_in[2];
    const float* b_r1    = (const float*)d_in[3];
    const float* W_r2    = (const float*)d_in[4];
    const float* W_up    = (const float*)d_in[5];
    const float* W_sc    = (const float*)d_in[6];
    const float* W_prod  = (const float*)d_in[7];
    const float* w_ro    = (const float*)d_in[8];
    const int* atom_types = (const int*)d_in[9];
    const int* eidx       = (const int*)d_in[10];
    const int* batch      = (const int*)d_in[11];
    float* out = (float*)d_out;

    k_zero<<<(Nn + 255) / 256, 256, 0, stream>>>(out, out_size);
    k_deg<<<Ee / 256, 256, 0, stream>>>(eidx);
    k_scan<<<1, 1024, 0, stream>>>();
    k_fill<<<Ee / 256, 256, 0, stream>>>(eidx);
    k_edge<<<(Ee / 2 + 255) / 256, 256, 0, stream>>>(pos, W_r1, b_r1, W_r2, eidx);
    k_hinit<<<(Nn * 64) / 256, 256, 0, stream>>>(W_embed, atom_types);
    for (int l = 0; l < 2; l++) {
        k_lin<<<Nn / 4, 256, 0, stream>>>(W_up + l * 4096, W_sc + l * 4096, l);
        k_node<<<Nn / 4, 256, 0, stream>>>(W_prod + l * 4096, w_ro + l * 64, batch, l, out);
    }
}

// Round 4
// 324.062 us; speedup vs baseline: 1.0971x; 1.0845x over previous
//
#include <hip/hip_runtime.h>
#include <math.h>

#define Nn 10000
#define Ee 160000
#define NBb 8

// Static device scratch — slot-ordered (CSR order) edge data for streaming reads.
__device__ __align__(16) float g_shc[Ee * 12];  // [slot][12] (9 used, pad to 48B)
__device__ __align__(16) float g_Rc[Ee * 64];   // [slot][64]
__device__ int   g_src[Ee];                     // [slot] sender node
__device__ float g_h[2][Nn * 64];
__device__ float g_h1[Nn * 64];
__device__ float g_hsc[Nn * 64];
__device__ int   g_deg[Nn];
__device__ int   g_offs[Nn + 1];
__device__ int   g_cursor[Nn];
__device__ int   g_csr[Ee];
__device__ float g_W1T[64 * NBb];               // W_r1 transposed: [j][k]

__global__ __launch_bounds__(256) void k_zero(float* out, int out_size) {
    int i = blockIdx.x * 256 + threadIdx.x;
    if (i < out_size) out[i] = 0.0f;
    if (i < Nn) { g_deg[i] = 0; g_cursor[i] = 0; }
}

// degree count; block 0 also transposes W_r1 -> g_W1T (runs before k_edge)
__global__ __launch_bounds__(256) void k_deg(const int* __restrict__ eidx,
                                             const float* __restrict__ Wr1) {
    int e = blockIdx.x * 256 + threadIdx.x;
    if (e < Ee) atomicAdd(&g_deg[eidx[Ee + e]], 1);
    if (blockIdx.x == 0) {
        for (int i = threadIdx.x; i < 64 * NBb; i += 256) {
            int k = i >> 6, j = i & 63;  // Wr1[k][j]
            g_W1T[j * NBb + k] = Wr1[i];
        }
    }
}

__global__ __launch_bounds__(1024) void k_scan() {
    __shared__ int part[1024];
    int t = threadIdx.x;
    const int CH = (Nn + 1023) / 1024;  // 10
    int st = t * CH;
    int en = st + CH; if (en > Nn) en = Nn;
    int s = 0;
    for (int i = st; i < en; i++) s += g_deg[i];
    part[t] = s;
    __syncthreads();
    for (int d = 1; d < 1024; d <<= 1) {
        int v = (t >= d) ? part[t - d] : 0;
        __syncthreads();
        part[t] += v;
        __syncthreads();
    }
    int base = (t == 0) ? 0 : part[t - 1];
    for (int i = st; i < en; i++) { g_offs[i] = base; base += g_deg[i]; }
    if (t == 1023) g_offs[Nn] = part[1023];
}

__global__ __launch_bounds__(256) void k_fill(const int* __restrict__ eidx) {
    int e = blockIdx.x * 256 + threadIdx.x;
    if (e >= Ee) return;
    int r = eidx[Ee + e];
    int p = g_offs[r] + atomicAdd(&g_cursor[r], 1);
    g_csr[p] = e;
}

// Per-edge geometry + radial MLP, written in CSR slot order.
// Weights read via wave-uniform indices -> scalar loads (s_load), no LDS.
__global__ __launch_bounds__(256) void k_edge(const float* __restrict__ pos,
                                              const float* __restrict__ br1,
                                              const float* __restrict__ Wr2,
                                              const int* __restrict__ eidx) {
    int s = blockIdx.x * 256 + threadIdx.x;
    if (s >= Ee) return;
    int e = g_csr[s];
    int snd = eidx[e];
    int rcv = eidx[Ee + e];
    float vx = pos[3 * rcv + 0] - pos[3 * snd + 0];
    float vy = pos[3 * rcv + 1] - pos[3 * snd + 1];
    float vz = pos[3 * rcv + 2] - pos[3 * snd + 2];
    float r = sqrtf(vx * vx + vy * vy + vz * vz);
    float inv = __builtin_amdgcn_rcpf(fmaxf(r, 1e-9f));
    float x = vx * inv, y = vy * inv, z = vz * inv;
    const float s3 = 1.7320508f;
    float4* shp = (float4*)(g_shc + (size_t)s * 12);
    shp[0] = make_float4(1.0f, x, y, z);
    shp[1] = make_float4(s3 * x * y, s3 * y * z, 0.5f * (3.0f * z * z - 1.0f), s3 * x * z);
    shp[2] = make_float4(0.5f * s3 * (x * x - y * y), 0.0f, 0.0f, 0.0f);
    g_src[s] = snd;

    float xx = r * 0.2f;
    float env = 0.0f;
    if (xx < 1.0f) {
        float x2 = xx * xx;
        float x6 = x2 * x2 * x2;
        float x7 = x6 * xx;
        float x8 = x7 * xx;
        env = 1.0f - 28.0f * x6 + 48.0f * x7 - 21.0f * x8;
    }
    const float pref = 0.63245553f;  // sqrt(2/R_MAX)
    const float PI_F = 3.14159265358979f;
    float fac = pref * inv * env;
    float ef[NBb];
#pragma unroll
    for (int k = 0; k < NBb; k++)
        ef[k] = fac * __sinf((float)(k + 1) * PI_F * r * 0.2f);

    float4 acc[16];
#pragma unroll
    for (int c = 0; c < 16; c++) acc[c] = make_float4(0.f, 0.f, 0.f, 0.f);

    for (int j = 0; j < 64; j++) {
        float a = br1[j];
#pragma unroll
        for (int k = 0; k < NBb; k++) a += ef[k] * g_W1T[j * NBb + k];
        // silu via fast intrinsics (1 exp + 1 rcp)
        a = a * __builtin_amdgcn_rcpf(1.0f + __expf(-a));
        const float* __restrict__ w2 = Wr2 + j * 64;
#pragma unroll
        for (int c = 0; c < 16; c++) {
            acc[c].x += a * w2[4 * c + 0];
            acc[c].y += a * w2[4 * c + 1];
            acc[c].z += a * w2[4 * c + 2];
            acc[c].w += a * w2[4 * c + 3];
        }
    }
    float4* dst = (float4*)(g_Rc + (size_t)s * 64);
#pragma unroll
    for (int c = 0; c < 16; c++) dst[c] = acc[c];
}

__global__ __launch_bounds__(256) void k_hinit(const float* __restrict__ W_embed,
                                               const int* __restrict__ atom_types) {
    int i = blockIdx.x * 256 + threadIdx.x;
    if (i >= Nn * 64) return;
    int n = i >> 6, c = i & 63;
    g_h[0][i] = W_embed[atom_types[n] * 64 + c];
}

__global__ __launch_bounds__(256) void k_lin(const float* __restrict__ Wup,
                                             const float* __restrict__ Wsc, int l) {
    __shared__ float sU[4096];
    __shared__ float sS[4096];
    int t = threadIdx.x;
    for (int i = t; i < 4096; i += 256) { sU[i] = Wup[i]; sS[i] = Wsc[i]; }
    __syncthreads();
    int node = blockIdx.x * 4 + (t >> 6);
    int lane = t & 63;
    const float* hin = g_h[l & 1];
    float hv = hin[node * 64 + lane];
    float a1 = 0.0f, a2 = 0.0f;
#pragma unroll
    for (int k = 0; k < 64; k++) {
        float hk = __shfl(hv, k, 64);
        a1 += hk * sU[k * 64 + lane];
        a2 += hk * sS[k * 64 + lane];
    }
    g_h1[node * 64 + lane] = a1;
    g_hsc[node * 64 + lane] = a2;
}

// Streaming gather: R/sh/src are in CSR order -> sequential; only h1 is a gather.
__global__ __launch_bounds__(256) void k_node(const float* __restrict__ Wprod,
                                              const float* __restrict__ wro,
                                              const int* __restrict__ batch,
                                              int l, float* __restrict__ out) {
    __shared__ float sP[4096];
    int t = threadIdx.x;
    for (int i = t; i < 4096; i += 256) sP[i] = Wprod[i];
    __syncthreads();
    int node = blockIdx.x * 4 + (t >> 6);
    int lane = t & 63;
    int beg = __builtin_amdgcn_readfirstlane(g_offs[node]);
    int en  = __builtin_amdgcn_readfirstlane(g_offs[node + 1]);
    float A[9];
#pragma unroll
    for (int m = 0; m < 9; m++) A[m] = 0.0f;

    int j = beg;
    for (; j + 2 <= en; j += 2) {
        int s0 = __builtin_amdgcn_readfirstlane(g_src[j]);
        int s1 = __builtin_amdgcn_readfirstlane(g_src[j + 1]);
        float r0 = g_Rc[(size_t)j * 64 + lane];
        float r1 = g_Rc[(size_t)(j + 1) * 64 + lane];
        float h0 = g_h1[s0 * 64 + lane];
        float h1v = g_h1[s1 * 64 + lane];
        const float4* p0 = (const float4*)(g_shc + (size_t)j * 12);
        const float4* p1 = (const float4*)(g_shc + (size_t)(j + 1) * 12);
        float4 u0 = p0[0], u1 = p0[1], u2 = p0[2];
        float4 v0 = p1[0], v1 = p1[1], v2 = p1[2];
        float tv0 = r0 * h0, tv1 = r1 * h1v;
        A[0] += u0.x * tv0 + v0.x * tv1;
        A[1] += u0.y * tv0 + v0.y * tv1;
        A[2] += u0.z * tv0 + v0.z * tv1;
        A[3] += u0.w * tv0 + v0.w * tv1;
        A[4] += u1.x * tv0 + v1.x * tv1;
        A[5] += u1.y * tv0 + v1.y * tv1;
        A[6] += u1.z * tv0 + v1.z * tv1;
        A[7] += u1.w * tv0 + v1.w * tv1;
        A[8] += u2.x * tv0 + v2.x * tv1;
    }
    for (; j < en; j++) {
        int s0 = __builtin_amdgcn_readfirstlane(g_src[j]);
        float tv = g_Rc[(size_t)j * 64 + lane] * g_h1[s0 * 64 + lane];
        const float4* p0 = (const float4*)(g_shc + (size_t)j * 12);
        float4 u0 = p0[0], u1 = p0[1], u2 = p0[2];
        A[0] += u0.x * tv; A[1] += u0.y * tv; A[2] += u0.z * tv;
        A[3] += u0.w * tv; A[4] += u1.x * tv; A[5] += u1.y * tv;
        A[6] += u1.z * tv; A[7] += u1.w * tv; A[8] += u2.x * tv;
    }

    const float invn = 1.0f / 16.0f;  // AVG_NEI
    float q = A[0] * invn;
#pragma unroll
    for (int m = 0; m < 9; m++) {
        float a = A[m] * invn;
        q += a * a;
    }
    float hn = g_hsc[node * 64 + lane];
#pragma unroll
    for (int k = 0; k < 64; k++) {
        float qk = __shfl(q, k, 64);
        hn += qk * sP[k * 64 + lane];
    }
    float* hout = g_h[(l + 1) & 1];
    hout[node * 64 + lane] = hn;
    float v = hn * wro[lane];
#pragma unroll
    for (int off = 32; off > 0; off >>= 1) v += __shfl_down(v, off, 64);
    if (lane == 0) atomicAdd(&out[batch[node]], v);
}

extern "C" void kernel_launch(void* const* d_in, const int* in_sizes, int n_in,
                              void* d_out, int out_size, void* d_ws, size_t ws_size,
                              hipStream_t stream) {
    const float* pos     = (const float*)d_in[0];
    const float* W_embed = (const float*)d_in[1];
    const float* W_r1    = (const float*)d_in[2];
    const float* b_r1    = (const float*)d_in[3];
    const float* W_r2    = (const float*)d_in[4];
    const float* W_up    = (const float*)d_in[5];
    const float* W_sc    = (const float*)d_in[6];
    const float* W_prod  = (const float*)d_in[7];
    const float* w_ro    = (const float*)d_in[8];
    const int* atom_types = (const int*)d_in[9];
    const int* eidx       = (const int*)d_in[10];
    const int* batch      = (const int*)d_in[11];
    float* out = (float*)d_out;

    k_zero<<<(Nn + 255) / 256, 256, 0, stream>>>(out, out_size);
    k_deg<<<Ee / 256, 256, 0, stream>>>(eidx, W_r1);
    k_scan<<<1, 1024, 0, stream>>>();
    k_fill<<<Ee / 256, 256, 0, stream>>>(eidx);
    k_edge<<<Ee / 256, 256, 0, stream>>>(pos, b_r1, W_r2, eidx);
    k_hinit<<<(Nn * 64) / 256, 256, 0, stream>>>(W_embed, atom_types);
    for (int l = 0; l < 2; l++) {
        k_lin<<<Nn / 4, 256, 0, stream>>>(W_up + l * 4096, W_sc + l * 4096, l);
        k_node<<<Nn / 4, 256, 0, stream>>>(W_prod + l * 4096, w_ro + l * 64, batch, l, out);
    }
}